// Round 14
// baseline (1113.577 us; speedup 1.0000x reference)
//
#include <hip/hip_runtime.h>

// Problem constants (match reference)
#define SEQ 2048
#define BAT 256
#define KD  64
#define HD  128

typedef _Float16 half2v  __attribute__((ext_vector_type(2)));  // fdot2 operand type
typedef __fp16   fp16x2  __attribute__((ext_vector_type(2)));  // cvt_pkrtz return type

// DPP helpers. CTRL: 0xB1 = quad_perm(1,0,3,2) = lane^1; 0x4E = quad_perm(2,3,0,1)
// = lane^2; 0x128 = row_ror:8 = lane^8 within 16-lane row; 0x124/0x12C =
// row_ror:4 / row_ror:12 (pair + select = lane^4 exchange, HW-validated r8+).
template<int CTRL>
__device__ __forceinline__ float dpp_add(float keep, float send) {
    const int r = __builtin_amdgcn_update_dpp(0, __float_as_int(send),
                                              CTRL, 0xF, 0xF, true);
    return keep + __int_as_float(r);
}
template<int CTRL>
__device__ __forceinline__ float dpp_mov(float send) {
    const int r = __builtin_amdgcn_update_dpp(0, __float_as_int(send),
                                              CTRL, 0xF, 0xF, true);
    return __int_as_float(r);
}

// Pack two f32 -> f16x2 bits (v_cvt_pkrtz_f16_f32).
__device__ __forceinline__ int PK(float a, float b) {
    fp16x2 p = __builtin_amdgcn_cvt_pkrtz(a, b);
    return __builtin_bit_cast(int, p);
}

// f32 += dot2(f16x2, f16x2) — v_dot2_f32_f16, f32 accumulate.
__device__ __forceinline__ float fdot2(int w, int h, float c) {
#if __has_builtin(__builtin_amdgcn_fdot2)
    return __builtin_amdgcn_fdot2(__builtin_bit_cast(half2v, w),
                                  __builtin_bit_cast(half2v, h), c, false);
#else
    half2v wv = __builtin_bit_cast(half2v, w), hv = __builtin_bit_cast(half2v, h);
    return fmaf((float)wv[1], (float)hv[1], fmaf((float)wv[0], (float)hv[0], c));
#endif
}

// Pin a scalar into a register (loads can't sink past the volatile asm).
#define PIN(x) asm volatile("" : "+v"(x))

// LDS-visibility-only barrier: does NOT drain vmcnt (output stores stay in
// flight; they need no ordering with the barrier).
#define STEP_BARRIER() do {                                   \
    asm volatile("s_waitcnt lgkmcnt(0)" ::: "memory");        \
    __builtin_amdgcn_s_barrier();                             \
    asm volatile("" ::: "memory");                            \
} while (0)

// ---------------------------------------------------------------------------
// Kernel 1: precompute type-dependent tables into d_ws (f32).
//   tabH[ty][r] = sum_k embed_W[ty][k]*W_ih[r][k] + b_ih[r] + b_hh[r]
//   tabD[ty][r] = sum_k embed_W[ty][k]*dec_W[r][k] + dec_b[r]
// ---------------------------------------------------------------------------
__global__ __launch_bounds__(128) void precompute_tables(
    const float* __restrict__ embed_W, const float* __restrict__ W_ih,
    const float* __restrict__ b_ih,    const float* __restrict__ b_hh,
    const float* __restrict__ dec_W,   const float* __restrict__ dec_b,
    float* __restrict__ tabH, float* __restrict__ tabD)
{
    __shared__ float x[KD];
    const int ty = blockIdx.x;   // 0..64 (row 64 = padding, embed row is zero)
    const int r  = threadIdx.x;  // 0..127
    if (r < KD) x[r] = embed_W[ty * KD + r];
    __syncthreads();
    float ah = 0.f, ad = 0.f;
#pragma unroll
    for (int k = 0; k < KD; ++k) {
        const float xv = x[k];
        ah += xv * W_ih[r * KD + k];
        ad += xv * dec_W[r * (KD + HD) + k];
    }
    tabH[ty * HD + r] = ah + b_ih[r] + b_hh[r];
    tabD[ty * HD + r] = ad + dec_b[r];
}

// ---------------------------------------------------------------------------
// Kernel 2: persistent per-batch-element recurrence. One WG per batch elem,
// 512 threads = 8 waves. vs round 8 (1007 us): the LDS pipe (~400 cyc/step,
// single pipe/CU, all pre-barrier) is the dominant serial resource, so this
// round halves LDS instructions:
//  - b2 (type) is now ALSO a chunk bit: 16 chunks x 8 h-cols -> ONE
//    ds_read_b128 of h per lane (was 2). Each lane holds BOTH matrices'
//    weights for its half-chunk (same 32 dwords, same 32 fdot2).
//  - dt+ty packed int2 in LDS: ONE ds_read_b64 per step (was 3x b32).
// Reduction gains a 4th stage: xor1/xor2 value-halve rows, xor4 value-halves
// TYPE (row_ror:4/12 + select), xor8 plain add. Final lane layout identical
// to r8: row = 4G + 2*b0 + b1, type = b2, dup = b3 -> epilogue unchanged.
// h double-buffered LDS f16; one lgkm-only barrier per step; 2x unrolled.
// ---------------------------------------------------------------------------
__global__ __launch_bounds__(512, 2) void hawkes_rnn(
    const float* __restrict__ dt_g,  const float* __restrict__ h0,
    const float* __restrict__ W_hh,  const float* __restrict__ dec_W,
    const int*   __restrict__ seq_types,
    const float* __restrict__ tabH,  const float* __restrict__ tabD,
    float* __restrict__ out)
{
    __shared__ __align__(16) _Float16 h16[2][HD];   //    512 B
    __shared__ __align__(8) int2 dtty[SEQ + 2];     // 16,400 B {dt bits, ty}

    const int b    = blockIdx.x;
    const int tid  = threadIdx.x;
    const int lane = tid & 63;
    const int b0 = lane & 1, b1 = (lane >> 1) & 1;
    const int b2 = (lane >> 2) & 1, b3 = (lane >> 3) & 1;
    const int G    = (tid >> 6) * 4 + ((lane >> 4) & 3);  // row quad 0..31
    const int row  = 4 * G + 2 * b0 + b1;
    const int chunk = b0 | (b1 << 1) | (b2 << 2) | (b3 << 3); // h-col block /8
    const bool cls3 = (b2 & b3);                          // LDS-writer lane

    // Stage packed {dt, ty} pairs for this batch element.
    for (int t = tid; t < SEQ; t += 512) {
        dtty[t] = make_int2(__float_as_int(dt_g[(size_t)t * BAT + b]),
                            seq_types[(size_t)t * BAT + b]);
    }
    if (tid < 2) dtty[SEQ + tid] = make_int2(0, 0);   // prefetch-pad
    if (tid < HD) h16[0][tid] = (_Float16)h0[b * HD + tid];

    // Load + convert this lane's weight blocks (rows 4G..4G+3 x cols
    // 8*chunk..+7, BOTH matrices) to f16x2: 16 H dwords + 16 D dwords.
    const float* whB = W_hh  + (size_t)(4 * G) * HD        + 8 * chunk;
    const float* wdB = dec_W + (size_t)(4 * G) * (KD + HD) + KD + 8 * chunk;
#define LWROW(D0,D1,D2,D3,P) { \
    const float4 _x = *reinterpret_cast<const float4*>(P);       \
    const float4 _y = *reinterpret_cast<const float4*>((P) + 4); \
    D0 = PK(_x.x,_x.y); D1 = PK(_x.z,_x.w); D2 = PK(_y.x,_y.y); D3 = PK(_y.z,_y.w); }
    int h00,h01,h02,h03, h10,h11,h12,h13, h20,h21,h22,h23, h30,h31,h32,h33;
    int d00,d01,d02,d03, d10,d11,d12,d13, d20,d21,d22,d23, d30,d31,d32,d33;
    LWROW(h00,h01,h02,h03, whB + 0 * HD)
    LWROW(h10,h11,h12,h13, whB + 1 * HD)
    LWROW(h20,h21,h22,h23, whB + 2 * HD)
    LWROW(h30,h31,h32,h33, whB + 3 * HD)
    LWROW(d00,d01,d02,d03, wdB + 0 * (KD + HD))
    LWROW(d10,d11,d12,d13, wdB + 1 * (KD + HD))
    LWROW(d20,d21,d22,d23, wdB + 2 * (KD + HD))
    LWROW(d30,d31,d32,d33, wdB + 3 * (KD + HD))
#undef LWROW
    PIN(h00);PIN(h01);PIN(h02);PIN(h03); PIN(h10);PIN(h11);PIN(h12);PIN(h13);
    PIN(h20);PIN(h21);PIN(h22);PIN(h23); PIN(h30);PIN(h31);PIN(h32);PIN(h33);
    PIN(d00);PIN(d01);PIN(d02);PIN(d03); PIN(d10);PIN(d11);PIN(d12);PIN(d13);
    PIN(d20);PIN(d21);PIN(d22);PIN(d23); PIN(d30);PIN(d31);PIN(d32);PIN(d33);

    const float* tabp = (b2 ? tabD : tabH) + row;

    // Per-lane 32-bit element offset for the single global store this lane
    // owns (advanced by BAT*HD per step). Class 3 never stores.
    unsigned off = (unsigned)(b2 ? (b3 ? 0u : (unsigned)SEQ * BAT * HD)
                                 : (b3 ? 2u * SEQ * BAT * HD : 0u))
                   + (unsigned)(b * HD + row);

    __syncthreads();   // staging visible

    // Pipelines: pair (dt,ty) and tab, 2 steps ahead (tab is an L2 gather).
    int2 pr_cur = dtty[0];
    int2 pr_nxt = dtty[1];
    float tab_cur = tabp[pr_cur.y * HD];
    float tab_nxt = tabp[pr_nxt.y * HD];

#define DOT4(A,W0,W1,W2,W3) \
    A = fdot2(W0, hv.x, A); A = fdot2(W1, hv.y, A); \
    A = fdot2(W2, hv.z, A); A = fdot2(W3, hv.w, A);

#define STEP(P, TT) { \
    const int2 pr_pf = dtty[(TT) + 2];               /* one b64 */ \
    const float tab_pf = tabp[pr_pf.y * HD];         /* gather, use at TT+2 */ \
    const float dtv = __int_as_float(pr_cur.x); \
    /* h chunk: ONE broadcast ds_read_b128 (8 f16) */ \
    const int4 hv = *reinterpret_cast<const int4*>(&h16[P][chunk * 8]); \
    float aH0 = 0.f, aH1 = 0.f, aH2 = 0.f, aH3 = 0.f; \
    float aD0 = 0.f, aD1 = 0.f, aD2 = 0.f, aD3 = 0.f; \
    DOT4(aH0, h00,h01,h02,h03)  DOT4(aH1, h10,h11,h12,h13) \
    DOT4(aH2, h20,h21,h22,h23)  DOT4(aH3, h30,h31,h32,h33) \
    DOT4(aD0, d00,d01,d02,d03)  DOT4(aD1, d10,d11,d12,d13) \
    DOT4(aD2, d20,d21,d22,d23)  DOT4(aD3, d30,d31,d32,d33) \
    /* stage1 (xor1, b0): resolve row bit1 (value-halving) */ \
    const float tH0 = dpp_add<0xB1>(b0 ? aH2 : aH0, b0 ? aH0 : aH2); \
    const float tH1 = dpp_add<0xB1>(b0 ? aH3 : aH1, b0 ? aH1 : aH3); \
    const float tD0 = dpp_add<0xB1>(b0 ? aD2 : aD0, b0 ? aD0 : aD2); \
    const float tD1 = dpp_add<0xB1>(b0 ? aD3 : aD1, b0 ? aD1 : aD3); \
    /* stage2 (xor2, b1): resolve row bit0 */ \
    const float uH = dpp_add<0x4E>(b1 ? tH1 : tH0, b1 ? tH0 : tH1); \
    const float uD = dpp_add<0x4E>(b1 ? tD1 : tD0, b1 ? tD0 : tD1); \
    /* stage3 (xor4, b2): resolve TYPE (partner keeps its own type) */ \
    const float snd = b2 ? uH : uD; \
    const float r4  = dpp_mov<0x124>(snd); \
    const float r12 = dpp_mov<0x12C>(snd); \
    const float s   = (b2 ? uD : uH) + (b2 ? r12 : r4); \
    /* stage4 (xor8, b3): plain add completes the sum */ \
    const float sv = dpp_add<0x128>(s, s) + tab_cur; \
    /* activations (branchless; all lanes both paths) */ \
    const float e2 = __expf(2.f * sv); \
    const float vh = 1.f - __fdividef(2.f, e2 + 1.f);            /* tanh */ \
    const float z  = 10.f * sv; \
    const float em = __expf(-fabsf(z)); \
    const float sp = 0.1f * (fmaxf(z, 0.f) + __logf(1.f + em));  /* softplus10 */ \
    const float vd = __expf(-sp * dtv); \
    const float v  = b2 ? vd : vh; \
    /* type exchange lane^4: row_ror:4 / row_ror:12 + select */ \
    const float x4  = dpp_mov<0x124>(v); \
    const float x12 = dpp_mov<0x12C>(v); \
    const float cross = b2 ? x12 : x4; \
    const float hnew  = v * cross; \
    if (cls3) {                       /* LDS write FIRST: shortens barrier path */ \
        h16[(P) ^ 1][row] = (_Float16)hnew; \
    } else { \
        const float stv = b2 ? sp : (b3 ? hnew : v); \
        out[off] = stv; \
    } \
    off += BAT * HD; \
    pr_cur = pr_nxt;  pr_nxt = pr_pf; \
    tab_cur = tab_nxt; tab_nxt = tab_pf; \
    STEP_BARRIER(); \
}

    for (int t = 0; t < SEQ; t += 2) {
        STEP(0, t)
        STEP(1, t + 1)
    }
#undef STEP
#undef DOT4
}

extern "C" void kernel_launch(void* const* d_in, const int* in_sizes, int n_in,
                              void* d_out, int out_size, void* d_ws, size_t ws_size,
                              hipStream_t stream) {
    const float* dt        = (const float*)d_in[0];
    const float* h0        = (const float*)d_in[1];
    const float* embed_W   = (const float*)d_in[2];
    const float* W_ih      = (const float*)d_in[3];
    const float* b_ih      = (const float*)d_in[4];
    const float* W_hh      = (const float*)d_in[5];
    const float* b_hh      = (const float*)d_in[6];
    const float* dec_W     = (const float*)d_in[7];
    const float* dec_b     = (const float*)d_in[8];
    const int*   seq_types = (const int*)  d_in[9];
    float* out  = (float*)d_out;

    float* tabHw = (float*)d_ws;                 // [65][128]
    float* tabDw = tabHw + (KD + 1) * HD;        // [65][128]

    precompute_tables<<<KD + 1, 128, 0, stream>>>(embed_W, W_ih, b_ih, b_hh,
                                                  dec_W, dec_b, tabHw, tabDw);
    hawkes_rnn<<<BAT, 512, 0, stream>>>(dt, h0, W_hh, dec_W, seq_types,
                                        tabHw, tabDw, out);
}

// Round 16
// 972.296 us; speedup vs baseline: 1.1453x; 1.1453x over previous
//
#include <hip/hip_runtime.h>

// Problem constants (match reference)
#define SEQ 2048
#define BAT 256
#define KD  64
#define HD  128
#define SBH 67108864u   // SEQ*BAT*HD

typedef _Float16 half2v  __attribute__((ext_vector_type(2)));  // fdot2 operand type
typedef __fp16   fp16x2  __attribute__((ext_vector_type(2)));  // cvt_pkrtz return type

// ds_swizzle xor patterns (BitMode: (xor<<10)|(or<<5)|and, and=0x1F).
// XOR addressing is direction-unambiguous (unlike row_ror): lane i <-> i^4.
template<int PAT>
__device__ __forceinline__ float swz(float x) {
    return __int_as_float(__builtin_amdgcn_ds_swizzle(__float_as_int(x), PAT));
}
#define XOR4 0x101F

// DPP helpers. CTRL: 0xB1 = quad_perm(1,0,3,2) = lane^1; 0x4E = quad_perm(2,3,0,1)
// = lane^2 (explicit involutions, direction-proof); 0x128 = row_ror:8 = lane^8
// within a 16-lane row (self-inverse, direction-proof).
template<int CTRL>
__device__ __forceinline__ float dpp_add(float keep, float send) {
    const int r = __builtin_amdgcn_update_dpp(0, __float_as_int(send),
                                              CTRL, 0xF, 0xF, true);
    return keep + __int_as_float(r);
}
template<int CTRL>
__device__ __forceinline__ float dpp_mov(float send) {
    const int r = __builtin_amdgcn_update_dpp(0, __float_as_int(send),
                                              CTRL, 0xF, 0xF, true);
    return __int_as_float(r);
}

// Pack two f32 -> f16x2 bits (v_cvt_pkrtz_f16_f32).
__device__ __forceinline__ int PK(float a, float b) {
    fp16x2 p = __builtin_amdgcn_cvt_pkrtz(a, b);
    return __builtin_bit_cast(int, p);
}

// f32 += dot2(f16x2, f16x2) — v_dot2_f32_f16, f32 accumulate.
__device__ __forceinline__ float fdot2(int w, int h, float c) {
#if __has_builtin(__builtin_amdgcn_fdot2)
    return __builtin_amdgcn_fdot2(__builtin_bit_cast(half2v, w),
                                  __builtin_bit_cast(half2v, h), c, false);
#else
    half2v wv = __builtin_bit_cast(half2v, w), hv = __builtin_bit_cast(half2v, h);
    return fmaf((float)wv[1], (float)hv[1], fmaf((float)wv[0], (float)hv[0], c));
#endif
}

// Pin a scalar into a register (loads can't sink past the volatile asm).
#define PIN(x) asm volatile("" : "+v"(x))
#define PIN4(v4) PIN(v4.x); PIN(v4.y); PIN(v4.z); PIN(v4.w)

// LDS-visibility-only barrier: does NOT drain vmcnt (output stores stay in
// flight; they need no ordering with the barrier).
#define STEP_BARRIER() do {                                   \
    asm volatile("s_waitcnt lgkmcnt(0)" ::: "memory");        \
    __builtin_amdgcn_s_barrier();                             \
    asm volatile("" ::: "memory");                            \
} while (0)

// ---------------------------------------------------------------------------
// Kernel 1: precompute type-dependent tables into d_ws (f32).
//   tabH[ty][r] = sum_k embed_W[ty][k]*W_ih[r][k] + b_ih[r] + b_hh[r]
//   tabD[ty][r] = sum_k embed_W[ty][k]*dec_W[r][k] + dec_b[r]
// ---------------------------------------------------------------------------
__global__ __launch_bounds__(128) void precompute_tables(
    const float* __restrict__ embed_W, const float* __restrict__ W_ih,
    const float* __restrict__ b_ih,    const float* __restrict__ b_hh,
    const float* __restrict__ dec_W,   const float* __restrict__ dec_b,
    float* __restrict__ tabH, float* __restrict__ tabD)
{
    __shared__ float x[KD];
    const int ty = blockIdx.x;   // 0..64 (row 64 = padding, embed row is zero)
    const int r  = threadIdx.x;  // 0..127
    if (r < KD) x[r] = embed_W[ty * KD + r];
    __syncthreads();
    float ah = 0.f, ad = 0.f;
#pragma unroll
    for (int k = 0; k < KD; ++k) {
        const float xv = x[k];
        ah += xv * W_ih[r * KD + k];
        ad += xv * dec_W[r * (KD + HD) + k];
    }
    tabH[ty * HD + r] = ah + b_ih[r] + b_hh[r];
    tabD[ty * HD + r] = ad + dec_b[r];
}

// ---------------------------------------------------------------------------
// Kernel 2: persistent per-batch-element recurrence. One WG per batch elem,
// 256 threads = 4 WAVES (r8/r12/r14 evidence: step time tracks per-CU totals
// of VALU+LDS+trans summed over lockstep waves -> fewer waves, more dots/lane).
// Lane bits (lane = tid&63):
//   b0,b1,b2 = chunk bits (chunk 0..7, 16 h-cols each) AND row bits 2,1,0
//   b3       = type (0=hidden/W_hh, 1=decay/dec_W)
//   bits 4-5 + wave: row group g = wave*4 + (lane>>4), rows 8g..8g+7
// Each lane: 8 rows x 16 cols of ONE type = 64 fdot2, 64 pinned weight dwords.
// Reduction: 3 value-halving stages — xor1/xor2 via quad_perm (direction-proof
// involutions), xor4 via ds_swizzle (XOR addressing; the r15 bug was using
// row_ror:4/12 here, whose direction convention silently mixed hidden and
// decay partials in this no-duplicate layout). Lane then holds the FULL
// preact for (row = 8g+4b0+2b1+b2, type = b3).
// Type exchange for h_new: one dpp row_ror:8 (lane^8, self-inverse -> safe).
// Per lane: b3=0 stores hidden + hidden_ti + LDS h-write; b3=1 stores decay.
// h double-buffered LDS f16; dt/ty packed int2 (one b64/step); one lgkm-only
// barrier per step; 2x unrolled for buffer parity.
// ---------------------------------------------------------------------------
__global__ __launch_bounds__(256, 1) void hawkes_rnn(
    const float* __restrict__ dt_g,  const float* __restrict__ h0,
    const float* __restrict__ W_hh,  const float* __restrict__ dec_W,
    const int*   __restrict__ seq_types,
    const float* __restrict__ tabH,  const float* __restrict__ tabD,
    float* __restrict__ out)
{
    __shared__ __align__(16) _Float16 h16[2][HD];   //    512 B
    __shared__ __align__(8) int2 dtty[SEQ + 2];     // 16,400 B {dt bits, ty}

    const int b    = blockIdx.x;
    const int tid  = threadIdx.x;
    const int lane = tid & 63;
    const int b0 = lane & 1, b1 = (lane >> 1) & 1;
    const int b2 = (lane >> 2) & 1, b3 = (lane >> 3) & 1;
    const int g    = (tid >> 6) * 4 + (lane >> 4);        // row group 0..15
    const int row  = 8 * g + 4 * b0 + 2 * b1 + b2;        // row this lane owns
    const int chunk = b0 | (b1 << 1) | (b2 << 2);         // h-col block /16

    // Stage packed {dt, ty} pairs for this batch element.
    for (int t = tid; t < SEQ; t += 256) {
        dtty[t] = make_int2(__float_as_int(dt_g[(size_t)t * BAT + b]),
                            seq_types[(size_t)t * BAT + b]);
    }
    if (tid < 2) dtty[SEQ + tid] = make_int2(0, 0);   // prefetch-pad
    if (tid < HD) h16[0][tid] = (_Float16)h0[b * HD + tid];

    // Load + convert this lane's weight block (rows 8g..8g+7 x cols
    // 16*chunk..+15 of its type's matrix) to f16x2: 64 pinned dwords.
    const size_t rstr = b3 ? (size_t)(KD + HD) : (size_t)HD;
    const float* wb = (b3 ? (dec_W + KD) : W_hh) + (size_t)(8 * g) * rstr
                      + chunk * 16;
#define LWROW(DA, DB, P) { \
    const float4 _a = *reinterpret_cast<const float4*>(P);        \
    const float4 _b = *reinterpret_cast<const float4*>((P) + 4);  \
    const float4 _c = *reinterpret_cast<const float4*>((P) + 8);  \
    const float4 _d = *reinterpret_cast<const float4*>((P) + 12); \
    DA = make_int4(PK(_a.x,_a.y), PK(_a.z,_a.w), PK(_b.x,_b.y), PK(_b.z,_b.w)); \
    DB = make_int4(PK(_c.x,_c.y), PK(_c.z,_c.w), PK(_d.x,_d.y), PK(_d.z,_d.w)); }
    int4 w0a,w0b,w1a,w1b,w2a,w2b,w3a,w3b,w4a,w4b,w5a,w5b,w6a,w6b,w7a,w7b;
    LWROW(w0a,w0b, wb + 0 * rstr)  LWROW(w1a,w1b, wb + 1 * rstr)
    LWROW(w2a,w2b, wb + 2 * rstr)  LWROW(w3a,w3b, wb + 3 * rstr)
    LWROW(w4a,w4b, wb + 4 * rstr)  LWROW(w5a,w5b, wb + 5 * rstr)
    LWROW(w6a,w6b, wb + 6 * rstr)  LWROW(w7a,w7b, wb + 7 * rstr)
#undef LWROW
    PIN4(w0a); PIN4(w0b); PIN4(w1a); PIN4(w1b);
    PIN4(w2a); PIN4(w2b); PIN4(w3a); PIN4(w3b);
    PIN4(w4a); PIN4(w4b); PIN4(w5a); PIN4(w5b);
    PIN4(w6a); PIN4(w6b); PIN4(w7a); PIN4(w7b);

    const float* tabp = (b3 ? tabD : tabH) + row;

    // Per-lane element offset of this lane's row in the hidden output plane
    // (advanced by BAT*HD per step). decay = +SBH, hidden_ti = +2*SBH.
    unsigned off = (unsigned)(b * HD + row);

    __syncthreads();   // staging visible

    // Pipelines: (dt,ty) pair and tab gather, 2 steps ahead (L2-resident).
    int2 pr_cur = dtty[0];
    int2 pr_nxt = dtty[1];
    float tab_cur = tabp[pr_cur.y * HD];
    float tab_nxt = tabp[pr_nxt.y * HD];

#define DOT16(A, WA, WB) \
    A = fdot2(WA.x, hv0.x, A); A = fdot2(WA.y, hv0.y, A); \
    A = fdot2(WA.z, hv0.z, A); A = fdot2(WA.w, hv0.w, A); \
    A = fdot2(WB.x, hv1.x, A); A = fdot2(WB.y, hv1.y, A); \
    A = fdot2(WB.z, hv1.z, A); A = fdot2(WB.w, hv1.w, A);

#define STEP(P, TT) { \
    const int2 pr_pf = dtty[(TT) + 2];               /* one b64 read */ \
    const float tab_pf = tabp[pr_pf.y * HD];         /* L2 gather, use TT+2 */ \
    const float dtv = __int_as_float(pr_cur.x); \
    /* h chunk: 2 broadcast ds_read_b128 (16 f16, 32B stride: free 2-way) */ \
    const int4 hv0 = *reinterpret_cast<const int4*>(&h16[P][chunk * 16]); \
    const int4 hv1 = *reinterpret_cast<const int4*>(&h16[P][chunk * 16 + 8]); \
    float a0 = 0.f, a1 = 0.f, a2 = 0.f, a3 = 0.f; \
    float a4 = 0.f, a5 = 0.f, a6 = 0.f, a7 = 0.f; \
    DOT16(a0, w0a, w0b)  DOT16(a1, w1a, w1b) \
    DOT16(a2, w2a, w2b)  DOT16(a3, w3a, w3b) \
    DOT16(a4, w4a, w4b)  DOT16(a5, w5a, w5b) \
    DOT16(a6, w6a, w6b)  DOT16(a7, w7a, w7b) \
    /* stage1 (xor1, b0): value-halve, resolve row bit2 */ \
    const float t0 = dpp_add<0xB1>(b0 ? a4 : a0, b0 ? a0 : a4); \
    const float t1 = dpp_add<0xB1>(b0 ? a5 : a1, b0 ? a1 : a5); \
    const float t2 = dpp_add<0xB1>(b0 ? a6 : a2, b0 ? a2 : a6); \
    const float t3 = dpp_add<0xB1>(b0 ? a7 : a3, b0 ? a3 : a7); \
    /* stage2 (xor2, b1): resolve row bit1 */ \
    const float u0 = dpp_add<0x4E>(b1 ? t2 : t0, b1 ? t0 : t2); \
    const float u1 = dpp_add<0x4E>(b1 ? t3 : t1, b1 ? t1 : t3); \
    /* stage3 (xor4, b2): resolve row bit0 via ds_swizzle XOR (exact) */ \
    const float snd = b2 ? u0 : u1; \
    const float sv  = (b2 ? u1 : u0) + swz<XOR4>(snd) + tab_cur; \
    /* activations (branchless; all lanes both paths) */ \
    const float e2 = __expf(2.f * sv); \
    const float vh = 1.f - __fdividef(2.f, e2 + 1.f);            /* tanh */ \
    const float z  = 10.f * sv; \
    const float em = __expf(-fabsf(z)); \
    const float sp = 0.1f * (fmaxf(z, 0.f) + __logf(1.f + em));  /* softplus10 */ \
    const float vd = __expf(-sp * dtv); \
    const float v  = b3 ? vd : vh; \
    /* type exchange lane^8 (row_ror:8, self-inverse): same row, other type */ \
    const float cross = dpp_mov<0x128>(v); \
    const float hnew  = v * cross; \
    if (b3 == 0) { \
        h16[(P) ^ 1][row] = (_Float16)hnew;   /* LDS write first */ \
        out[off] = v; \
        out[off + 2u * SBH] = hnew; \
    } else { \
        out[off + SBH] = sp; \
    } \
    off += BAT * HD; \
    pr_cur = pr_nxt;   pr_nxt = pr_pf; \
    tab_cur = tab_nxt; tab_nxt = tab_pf; \
    STEP_BARRIER(); \
}

    for (int t = 0; t < SEQ; t += 2) {
        STEP(0, t)
        STEP(1, t + 1)
    }
#undef STEP
#undef DOT16
}

extern "C" void kernel_launch(void* const* d_in, const int* in_sizes, int n_in,
                              void* d_out, int out_size, void* d_ws, size_t ws_size,
                              hipStream_t stream) {
    const float* dt        = (const float*)d_in[0];
    const float* h0        = (const float*)d_in[1];
    const float* embed_W   = (const float*)d_in[2];
    const float* W_ih      = (const float*)d_in[3];
    const float* b_ih      = (const float*)d_in[4];
    const float* W_hh      = (const float*)d_in[5];
    const float* b_hh      = (const float*)d_in[6];
    const float* dec_W     = (const float*)d_in[7];
    const float* dec_b     = (const float*)d_in[8];
    const int*   seq_types = (const int*)  d_in[9];
    float* out  = (float*)d_out;

    float* tabHw = (float*)d_ws;                 // [65][128]
    float* tabDw = tabHw + (KD + 1) * HD;        // [65][128]

    precompute_tables<<<KD + 1, 128, 0, stream>>>(embed_W, W_ih, b_ih, b_hh,
                                                  dec_W, dec_b, tabHw, tabDw);
    hawkes_rnn<<<BAT, 256, 0, stream>>>(dt, h0, W_hh, dec_W, seq_types,
                                        tabHw, tabDw, out);
}

// Round 17
// 824.385 us; speedup vs baseline: 1.3508x; 1.1794x over previous
//
#include <hip/hip_runtime.h>

// Problem constants (match reference)
#define SEQ 2048
#define BAT 256
#define KD  64
#define HD  128
#define SBH 67108864u   // SEQ*BAT*HD

typedef _Float16 half2v  __attribute__((ext_vector_type(2)));  // fdot2 operand type
typedef __fp16   fp16x2  __attribute__((ext_vector_type(2)));  // cvt_pkrtz return type
typedef unsigned uint2v  __attribute__((ext_vector_type(2)));  // permlane32_swap ret

// DPP helpers — ALL direction-proof: 0xB1 = quad_perm(1,0,3,2) = lane^1;
// 0x4E = quad_perm(2,3,0,1) = lane^2; 0x128 = row_ror:8 = lane^8 within a
// 16-lane row (rotation by half the row = involution either direction).
template<int CTRL>
__device__ __forceinline__ float dpp_add(float keep, float send) {
    const int r = __builtin_amdgcn_update_dpp(0, __float_as_int(send),
                                              CTRL, 0xF, 0xF, true);
    return keep + __int_as_float(r);
}

// lane^32 exchange via v_permlane32_swap_b32 (VALU pipe; self-symmetric:
// feeding v to both operands makes the two outputs [v.lo,v.lo] and
// [v.hi,v.hi]; select by own half).
__device__ __forceinline__ float xchg32(float v, int hi_half, int lane) {
#if __has_builtin(__builtin_amdgcn_permlane32_swap)
    uint2v r = __builtin_amdgcn_permlane32_swap(__float_as_uint(v),
                                                __float_as_uint(v),
                                                false, false);
    return __uint_as_float(hi_half ? r.x : r.y);
#else
    return __uint_as_float(__builtin_amdgcn_ds_bpermute(
        ((lane ^ 32) << 2), __float_as_uint(v)));
#endif
}

// Pack two f32 -> f16x2 bits (v_cvt_pkrtz_f16_f32).
__device__ __forceinline__ int PK(float a, float b) {
    fp16x2 p = __builtin_amdgcn_cvt_pkrtz(a, b);
    return __builtin_bit_cast(int, p);
}

// f32 += dot2(f16x2, f16x2) — v_dot2_f32_f16, f32 accumulate.
__device__ __forceinline__ float fdot2(int w, int h, float c) {
#if __has_builtin(__builtin_amdgcn_fdot2)
    return __builtin_amdgcn_fdot2(__builtin_bit_cast(half2v, w),
                                  __builtin_bit_cast(half2v, h), c, false);
#else
    half2v wv = __builtin_bit_cast(half2v, w), hv = __builtin_bit_cast(half2v, h);
    return fmaf((float)wv[1], (float)hv[1], fmaf((float)wv[0], (float)hv[0], c));
#endif
}

// Pin a scalar into a register (loads can't sink past the volatile asm).
#define PIN(x) asm volatile("" : "+v"(x))
#define PIN4(v4) PIN(v4.x); PIN(v4.y); PIN(v4.z); PIN(v4.w)

// LDS-visibility-only barrier: does NOT drain vmcnt (output stores stay in
// flight; with tables in LDS the loop has NO VMEM loads, so vmcnt is never
// waited on anywhere in the loop).
#define STEP_BARRIER() do {                                   \
    asm volatile("s_waitcnt lgkmcnt(0)" ::: "memory");        \
    __builtin_amdgcn_s_barrier();                             \
    asm volatile("" ::: "memory");                            \
} while (0)

// ---------------------------------------------------------------------------
// Kernel 1: precompute type-dependent tables into d_ws (f32).
//   tabH[ty][r] = sum_k embed_W[ty][k]*W_ih[r][k] + b_ih[r] + b_hh[r]
//   tabD[ty][r] = sum_k embed_W[ty][k]*dec_W[r][k] + dec_b[r]
// ---------------------------------------------------------------------------
__global__ __launch_bounds__(128) void precompute_tables(
    const float* __restrict__ embed_W, const float* __restrict__ W_ih,
    const float* __restrict__ b_ih,    const float* __restrict__ b_hh,
    const float* __restrict__ dec_W,   const float* __restrict__ dec_b,
    float* __restrict__ tabH, float* __restrict__ tabD)
{
    __shared__ float x[KD];
    const int ty = blockIdx.x;   // 0..64 (row 64 = padding, embed row is zero)
    const int r  = threadIdx.x;  // 0..127
    if (r < KD) x[r] = embed_W[ty * KD + r];
    __syncthreads();
    float ah = 0.f, ad = 0.f;
#pragma unroll
    for (int k = 0; k < KD; ++k) {
        const float xv = x[k];
        ah += xv * W_ih[r * KD + k];
        ad += xv * dec_W[r * (KD + HD) + k];
    }
    tabH[ty * HD + r] = ah + b_ih[r] + b_hh[r];
    tabD[ty * HD + r] = ad + dec_b[r];
}

// ---------------------------------------------------------------------------
// Kernel 2: persistent per-batch-element recurrence. One WG per batch elem,
// 256 threads = 4 waves (r16 structure). Round-17 changes, both aimed at the
// serial critical path (r16 is latency-bound: VALUBusy 53% at 1 wave/SIMD):
//  1. Reduction is ALL direction-proof VALU ops — no ds_swizzle (~100+ cyc
//     LDS round trip removed from the chain). Lane bits: reduction over
//     {b0: quad_perm xor1, b1: quad_perm xor2, b3: row_ror:8}; type at b5
//     with permlane32_swap exchange (VALU).
//  2. Bias tables staged in LDS as f16 -> the loop has NO VMEM loads; output
//     stores never get vmcnt-waited.
// Lane bits (lane = tid&63):
//   b0,b1,b3 = chunk bits AND resolved row bits (value-halving stages)
//   b2,b4    = static row bits;  b5 = type (0=hidden, 1=decay)
//   G = wave*4 + b4*2 + b2 (row octet), row = 8G + 4*b0 + 2*b1 + b3
//   chunk = b0 | b1<<1 | b3<<2  (8 chunks x 16 h-cols)
// Each lane: 8 rows x 16 cols of ONE type = 64 fdot2, 64 pinned weight dwords.
// b5=0 lanes: store hidden + hidden_ti + LDS h-write. b5=1: store decay.
// h double-buffered LDS f16; one lgkm-only barrier per step; 2x unrolled.
// ---------------------------------------------------------------------------
__global__ __launch_bounds__(256, 1) void hawkes_rnn(
    const float* __restrict__ dt_g,  const float* __restrict__ h0,
    const float* __restrict__ W_hh,  const float* __restrict__ dec_W,
    const int*   __restrict__ seq_types,
    const float* __restrict__ tabH,  const float* __restrict__ tabD,
    float* __restrict__ out)
{
    __shared__ __align__(16) _Float16 h16[2][HD];       //    512 B
    __shared__ __align__(8) int2 dtty[SEQ + 2];         // 16,400 B {dt, ty}
    __shared__ _Float16 tabLH[(KD + 1) * HD];           // 16,640 B
    __shared__ _Float16 tabLD[(KD + 1) * HD];           // 16,640 B  (tot ~50 KB)

    const int b    = blockIdx.x;
    const int tid  = threadIdx.x;
    const int lane = tid & 63;
    const int b0 = lane & 1, b1 = (lane >> 1) & 1;
    const int b2 = (lane >> 2) & 1, b3 = (lane >> 3) & 1;
    const int b4 = (lane >> 4) & 1, b5 = (lane >> 5) & 1;
    const int G     = (tid >> 6) * 4 + b4 * 2 + b2;       // row octet 0..15
    const int row   = 8 * G + 4 * b0 + 2 * b1 + b3;       // row this lane owns
    const int chunk = b0 | (b1 << 1) | (b3 << 2);         // h-col block /16

    // Stage packed {dt, ty} pairs + both bias tables (f32 -> f16) + h0.
    for (int t = tid; t < SEQ; t += 256) {
        dtty[t] = make_int2(__float_as_int(dt_g[(size_t)t * BAT + b]),
                            seq_types[(size_t)t * BAT + b]);
    }
    if (tid < 2) dtty[SEQ + tid] = make_int2(0, 0);   // prefetch-pad
    for (int i = tid; i < (KD + 1) * HD; i += 256) {
        tabLH[i] = (_Float16)tabH[i];
        tabLD[i] = (_Float16)tabD[i];
    }
    if (tid < HD) h16[0][tid] = (_Float16)h0[b * HD + tid];

    // Load + convert this lane's weight block (rows 8G..8G+7 x cols
    // 16*chunk..+15 of its type's matrix) to f16x2: 64 pinned dwords.
    const size_t rstr = b5 ? (size_t)(KD + HD) : (size_t)HD;
    const float* wb = (b5 ? (dec_W + KD) : W_hh) + (size_t)(8 * G) * rstr
                      + chunk * 16;
#define LWROW(DA, DB, P) { \
    const float4 _a = *reinterpret_cast<const float4*>(P);        \
    const float4 _b = *reinterpret_cast<const float4*>((P) + 4);  \
    const float4 _c = *reinterpret_cast<const float4*>((P) + 8);  \
    const float4 _d = *reinterpret_cast<const float4*>((P) + 12); \
    DA = make_int4(PK(_a.x,_a.y), PK(_a.z,_a.w), PK(_b.x,_b.y), PK(_b.z,_b.w)); \
    DB = make_int4(PK(_c.x,_c.y), PK(_c.z,_c.w), PK(_d.x,_d.y), PK(_d.z,_d.w)); }
    int4 w0a,w0b,w1a,w1b,w2a,w2b,w3a,w3b,w4a,w4b,w5a,w5b,w6a,w6b,w7a,w7b;
    LWROW(w0a,w0b, wb + 0 * rstr)  LWROW(w1a,w1b, wb + 1 * rstr)
    LWROW(w2a,w2b, wb + 2 * rstr)  LWROW(w3a,w3b, wb + 3 * rstr)
    LWROW(w4a,w4b, wb + 4 * rstr)  LWROW(w5a,w5b, wb + 5 * rstr)
    LWROW(w6a,w6b, wb + 6 * rstr)  LWROW(w7a,w7b, wb + 7 * rstr)
#undef LWROW
    PIN4(w0a); PIN4(w0b); PIN4(w1a); PIN4(w1b);
    PIN4(w2a); PIN4(w2b); PIN4(w3a); PIN4(w3b);
    PIN4(w4a); PIN4(w4b); PIN4(w5a); PIN4(w5b);
    PIN4(w6a); PIN4(w6b); PIN4(w7a); PIN4(w7b);

    const _Float16* tabp = (b5 ? tabLD : tabLH) + row;

    // Per-lane element offset of this lane's row in the hidden output plane
    // (advanced by BAT*HD per step). decay = +SBH, hidden_ti = +2*SBH.
    unsigned off = (unsigned)(b * HD + row);

    __syncthreads();   // staging visible

    // Pipelines: (dt,ty) pair and LDS tab read, 2 steps ahead.
    int2 pr_cur = dtty[0];
    int2 pr_nxt = dtty[1];
    float tab_cur = (float)tabp[pr_cur.y * HD];
    float tab_nxt = (float)tabp[pr_nxt.y * HD];

#define DOT16(A, WA, WB) \
    A = fdot2(WA.x, hv0.x, A); A = fdot2(WA.y, hv0.y, A); \
    A = fdot2(WA.z, hv0.z, A); A = fdot2(WA.w, hv0.w, A); \
    A = fdot2(WB.x, hv1.x, A); A = fdot2(WB.y, hv1.y, A); \
    A = fdot2(WB.z, hv1.z, A); A = fdot2(WB.w, hv1.w, A);

#define STEP(P, TT) { \
    const int2 pr_pf = dtty[(TT) + 2];               /* one b64 read */ \
    const float tab_pf = (float)tabp[pr_pf.y * HD];  /* LDS read, use TT+2 */ \
    const float dtv = __int_as_float(pr_cur.x); \
    /* h chunk: 2 broadcast ds_read_b128 (16 f16, 32B stride: free 2-way) */ \
    const int4 hv0 = *reinterpret_cast<const int4*>(&h16[P][chunk * 16]); \
    const int4 hv1 = *reinterpret_cast<const int4*>(&h16[P][chunk * 16 + 8]); \
    float a0 = 0.f, a1 = 0.f, a2 = 0.f, a3 = 0.f; \
    float a4 = 0.f, a5 = 0.f, a6 = 0.f, a7 = 0.f; \
    DOT16(a0, w0a, w0b)  DOT16(a1, w1a, w1b) \
    DOT16(a2, w2a, w2b)  DOT16(a3, w3a, w3b) \
    DOT16(a4, w4a, w4b)  DOT16(a5, w5a, w5b) \
    DOT16(a6, w6a, w6b)  DOT16(a7, w7a, w7b) \
    /* stage1 (xor1, b0, quad_perm): value-halve, resolve row bit2 */ \
    const float t0 = dpp_add<0xB1>(b0 ? a4 : a0, b0 ? a0 : a4); \
    const float t1 = dpp_add<0xB1>(b0 ? a5 : a1, b0 ? a1 : a5); \
    const float t2 = dpp_add<0xB1>(b0 ? a6 : a2, b0 ? a2 : a6); \
    const float t3 = dpp_add<0xB1>(b0 ? a7 : a3, b0 ? a3 : a7); \
    /* stage2 (xor2, b1, quad_perm): resolve row bit1 */ \
    const float u0 = dpp_add<0x4E>(b1 ? t2 : t0, b1 ? t0 : t2); \
    const float u1 = dpp_add<0x4E>(b1 ? t3 : t1, b1 ? t1 : t3); \
    /* stage3 (xor8, b3, row_ror:8 involution): resolve row bit0 */ \
    const float sv = dpp_add<0x128>(b3 ? u1 : u0, b3 ? u0 : u1) + tab_cur; \
    /* activations (branchless; all lanes both paths) */ \
    const float e2 = __expf(2.f * sv); \
    const float vh = 1.f - __fdividef(2.f, e2 + 1.f);            /* tanh */ \
    const float z  = 10.f * sv; \
    const float em = __expf(-fabsf(z)); \
    const float sp = 0.1f * (fmaxf(z, 0.f) + __logf(1.f + em));  /* softplus10 */ \
    const float vd = __expf(-sp * dtv); \
    const float v  = b5 ? vd : vh; \
    /* type exchange lane^32: permlane32_swap (VALU, self-symmetric) */ \
    const float cross = xchg32(v, b5, lane); \
    const float hnew  = v * cross; \
    if (b5 == 0) { \
        h16[(P) ^ 1][row] = (_Float16)hnew;   /* LDS write first */ \
        out[off] = v; \
        out[off + 2u * SBH] = hnew; \
    } else { \
        out[off + SBH] = sp; \
    } \
    off += BAT * HD; \
    pr_cur = pr_nxt;   pr_nxt = pr_pf; \
    tab_cur = tab_nxt; tab_nxt = tab_pf; \
    STEP_BARRIER(); \
}

    for (int t = 0; t < SEQ; t += 2) {
        STEP(0, t)
        STEP(1, t + 1)
    }
#undef STEP
#undef DOT16
}

extern "C" void kernel_launch(void* const* d_in, const int* in_sizes, int n_in,
                              void* d_out, int out_size, void* d_ws, size_t ws_size,
                              hipStream_t stream) {
    const float* dt        = (const float*)d_in[0];
    const float* h0        = (const float*)d_in[1];
    const float* embed_W   = (const float*)d_in[2];
    const float* W_ih      = (const float*)d_in[3];
    const float* b_ih      = (const float*)d_in[4];
    const float* W_hh      = (const float*)d_in[5];
    const float* b_hh      = (const float*)d_in[6];
    const float* dec_W     = (const float*)d_in[7];
    const float* dec_b     = (const float*)d_in[8];
    const int*   seq_types = (const int*)  d_in[9];
    float* out  = (float*)d_out;

    float* tabHw = (float*)d_ws;                 // [65][128]
    float* tabDw = tabHw + (KD + 1) * HD;        // [65][128]

    precompute_tables<<<KD + 1, 128, 0, stream>>>(embed_W, W_ih, b_ih, b_hh,
                                                  dec_W, dec_b, tabHw, tabDw);
    hawkes_rnn<<<BAT, 256, 0, stream>>>(dt, h0, W_hh, dec_W, seq_types,
                                        tabHw, tabDw, out);
}